// Round 1
// 477.512 us; speedup vs baseline: 1.0823x; 1.0823x over previous
//
#include <hip/hip_runtime.h>

typedef unsigned short u16;
typedef unsigned int   u32;
typedef __attribute__((ext_vector_type(8))) short short8;  // 8 bf16 (4 VGPRs)
typedef __attribute__((ext_vector_type(4))) float f32x4;
typedef __attribute__((ext_vector_type(4))) unsigned short us4;

#define MFMA16(a, b, c) __builtin_amdgcn_mfma_f32_16x16x32_bf16((a), (b), (c), 0, 0, 0)

static constexpr int B_ = 8;
static constexpr int HW = 3136;   // 56*56
static constexpr int KW = 784;    // 28*28
static constexpr int NELEM = B_ * 256 * HW;  // 6422528
static constexpr int NBB = 8 * HW * KW;      // Bbias elems: 19668992

// ---- workspace layout (bytes). Base needs ~39.1 MB; bf16-bias arena wants ~78.5 MB. ----
static constexpr size_t OFF_CNT = 4096;   // int: dtype-detect counter (>=64 -> f32 inputs)
static constexpr size_t OFF_W   = 8192;   // bf16 weight arena
// arena offsets in u16 units
static constexpr int AOFF_WQ = 0, AOFF_WK = 65536, AOFF_WV = 131072, AOFF_WO = 196608;
static constexpr int AOFF_WKDW = 262144, AOFF_WVDW = 264448;
static constexpr int AOFF_BKDW = 266752, AOFF_BVDW = 267008, AOFF_BQ = 267264;
static constexpr int AOFF_BK = 267520, AOFF_BV = 267776, AOFF_BO = 268032;
static constexpr size_t OFF_XT  = 557056;
static constexpr size_t SZ_XT   = (size_t)B_ * HW * 256 * 2;  // 12845056
static constexpr size_t SZ_KJ   = (size_t)B_ * KW * 256 * 2;  // 3211264
static constexpr size_t OFF_KIT = OFF_XT + SZ_XT;
static constexpr size_t OFF_VIT = OFF_KIT + SZ_KJ;
static constexpr size_t OFF_KI  = OFF_VIT + SZ_KJ;  // conv-k out, later reused for k-proj out
static constexpr size_t OFF_VI  = OFF_KI + SZ_KJ;   // conv-v out, later reused for vT
static constexpr size_t OFF_Q   = OFF_VI + SZ_KJ;
static constexpr size_t OFF_O   = OFF_XT;           // overlays xt (dead after proj_q)
static constexpr size_t OFF_BB  = OFF_Q + SZ_XT;    // 39092224: bf16 Bbias arena (optional)
static constexpr size_t SZ_BB   = (size_t)NBB * 2;  // 39337984

__device__ __forceinline__ float bf2f(u16 u) { return __uint_as_float(((u32)u) << 16); }
__device__ __forceinline__ u16 f2bf(float f) {
  u32 u = __float_as_uint(f);
  u32 r = u + 0x7FFFu + ((u >> 16) & 1u);
  return (u16)(r >> 16);
}
// HW packed f32->bf16 RNE (1 instr for 2 values); no builtin on gfx950, use asm.
__device__ __forceinline__ u32 cvtpk(float lo, float hi) {
  u32 r;
  asm("v_cvt_pk_bf16_f32 %0, %1, %2" : "=v"(r) : "v"(lo), "v"(hi));
  return r;
}

// ---- dtype detect: low 16 bits of first 4096 words of x, decoded as bf16.
__global__ __launch_bounds__(256) void detect_k(const u32* __restrict__ x, int* __restrict__ cnt) {
  int c = 0;
  for (int i = threadIdx.x; i < 4096; i += 256) {
    float v = __uint_as_float(x[i] << 16);
    if (fabsf(v) > 1e4f) c++;
  }
#pragma unroll
  for (int off = 32; off > 0; off >>= 1) c += __shfl_down(c, off);
  if ((threadIdx.x & 63) == 0) atomicAdd(cnt, c);
}

// ---- canonicalize 12 weight/bias tensors into bf16 arena ----
struct CvtArgs { const void* src[12]; int dstoff[12]; int n[12]; };
__global__ __launch_bounds__(256) void cvtw_k(CvtArgs a, u16* __restrict__ arena,
                                              const int* __restrict__ cnt) {
  int t = blockIdx.y;
  int n = a.n[t];
  u16* d = arena + a.dstoff[t];
  int f32m = (*cnt >= 64);
  if (f32m) {
    const float* s = (const float*)a.src[t];
    for (int i = blockIdx.x * 256 + threadIdx.x; i < n; i += gridDim.x * 256) d[i] = f2bf(s[i]);
  } else {
    const u16* s = (const u16*)a.src[t];
    for (int i = blockIdx.x * 256 + threadIdx.x; i < n; i += gridDim.x * 256) d[i] = s[i];
  }
}

// ---- Bbias -> bf16 arena (only launched when ws is big enough) ----
__global__ __launch_bounds__(256) void cvtb_k(const void* __restrict__ src, u16* __restrict__ dst,
                                              const int* __restrict__ cnt) {
  int f32m = (*cnt >= 64);
  const int n4 = NBB / 4;
  if (f32m) {
    const float4* s = (const float4*)src;
    us4* d = (us4*)dst;
    for (int i = blockIdx.x * 256 + threadIdx.x; i < n4; i += gridDim.x * 256) {
      float4 v = s[i];
      us4 o = {f2bf(v.x), f2bf(v.y), f2bf(v.z), f2bf(v.w)};
      d[i] = o;
    }
  } else {
    const uint2* s = (const uint2*)src;
    uint2* d = (uint2*)dst;
    for (int i = blockIdx.x * 256 + threadIdx.x; i < n4; i += gridDim.x * 256) d[i] = s[i];
  }
}

// ---- global sum / sumsq of x (single-scalar LayerNorm), dual dtype ----
__global__ __launch_bounds__(256) void reduce_k(const void* __restrict__ x, double* __restrict__ acc,
                                                const int* __restrict__ cnt) {
  int f32m = (*cnt >= 64);
  float s = 0.f, ss = 0.f;
  if (f32m) {
    const float4* xv = (const float4*)x;
    const int n4 = NELEM / 4;
    for (int i = blockIdx.x * 256 + threadIdx.x; i < n4; i += gridDim.x * 256) {
      float4 u = xv[i];
      s += u.x + u.y + u.z + u.w;
      ss += u.x * u.x + u.y * u.y + u.z * u.z + u.w * u.w;
    }
  } else {
    const uint4* xv = (const uint4*)x;
    const int n8 = NELEM / 8;
    for (int i = blockIdx.x * 256 + threadIdx.x; i < n8; i += gridDim.x * 256) {
      uint4 u = xv[i];
      u32 w[4] = {u.x, u.y, u.z, u.w};
#pragma unroll
      for (int q = 0; q < 4; q++) {
        float f0 = __uint_as_float(w[q] << 16);
        float f1 = __uint_as_float(w[q] & 0xFFFF0000u);
        s += f0 + f1;
        ss += f0 * f0 + f1 * f1;
      }
    }
  }
#pragma unroll
  for (int off = 32; off > 0; off >>= 1) {
    s += __shfl_down(s, off);
    ss += __shfl_down(ss, off);
  }
  __shared__ float as_[4], ass_[4];
  int wv = threadIdx.x >> 6;
  if ((threadIdx.x & 63) == 0) { as_[wv] = s; ass_[wv] = ss; }
  __syncthreads();
  if (threadIdx.x == 0) {
    atomicAdd(acc + 0, (double)(as_[0] + as_[1] + as_[2] + as_[3]));
    atomicAdd(acc + 1, (double)(ass_[0] + ass_[1] + ass_[2] + ass_[3]));
  }
}

// ---- mu/rstd + folded Q-projection constants (weights already bf16 in arena) ----
__global__ __launch_bounds__(256) void prep_k(const u16* __restrict__ wq, const u16* __restrict__ bq,
                                              float* __restrict__ wsf) {
  const double* acc = (const double*)wsf;
  __shared__ float sh[2];
  if (threadIdx.x == 0) {
    double N = (double)NELEM;
    double mu = acc[0] / N;
    double var = acc[1] / N - mu * mu;
    float rstd = (float)(1.0 / sqrt(var + 1e-5));
    sh[0] = (float)mu; sh[1] = rstd;
    wsf[4] = (float)mu; wsf[5] = rstd;
    wsf[6] = rstd * 0.17677669529663687f;  // rstd / sqrt(32)
  }
  __syncthreads();
  int o = threadIdx.x;
  float wsum = 0.f;
  for (int c = 0; c < 256; c++) wsum += bf2f(wq[o * 256 + c]);
  wsf[16 + o] = (bf2f(bq[o]) - sh[1] * sh[0] * wsum) * 0.17677669529663687f;
}

// ---- x [b][256][3136] -> xt [b][3136][256], dual dtype, bf16 out ----
__global__ __launch_bounds__(256) void transpose_x_k(const void* __restrict__ src, u16* __restrict__ dst,
                                                     const int* __restrict__ cnt) {
  int f32m = (*cnt >= 64);
  __shared__ u16 t[32][33];
  int b = blockIdx.z;
  int r0 = blockIdx.y * 32, c0 = blockIdx.x * 32;
  int tid = threadIdx.x, col = tid & 31;
  size_t base = (size_t)b * 256 * HW;
  if (f32m) {
    const float* s = (const float*)src + base;
#pragma unroll
    for (int i = 0; i < 4; i++) {
      int row = (tid >> 5) + i * 8;
      t[row][col] = f2bf(s[(size_t)(r0 + row) * HW + c0 + col]);
    }
  } else {
    const u16* s = (const u16*)src + base;
#pragma unroll
    for (int i = 0; i < 4; i++) {
      int row = (tid >> 5) + i * 8;
      t[row][col] = s[(size_t)(r0 + row) * HW + c0 + col];
    }
  }
  __syncthreads();
  u16* d = dst + base;
#pragma unroll
  for (int i = 0; i < 4; i++) {
    int row = (tid >> 5) + i * 8;  // indexes HW-dim in dst
    d[(size_t)(c0 + row) * 256 + r0 + col] = t[col][row];
  }
}

// ---- generic bf16 per-batch [R][Cc] -> [Cc][R] transpose (for conv outputs) ----
__global__ __launch_bounds__(256) void transpose_k(const u16* __restrict__ src, u16* __restrict__ dst,
                                                   int R, int Cc) {
  __shared__ u16 t[32][33];
  int b = blockIdx.z;
  int r0 = blockIdx.y * 32, c0 = blockIdx.x * 32;
  const u16* s = src + (size_t)b * R * Cc;
  u16* d = dst + (size_t)b * R * Cc;
  int tid = threadIdx.x, col = tid & 31;
#pragma unroll
  for (int i = 0; i < 4; i++) {
    int row = (tid >> 5) + i * 8;
    if (r0 + row < R && c0 + col < Cc) t[row][col] = s[(size_t)(r0 + row) * Cc + c0 + col];
  }
  __syncthreads();
#pragma unroll
  for (int i = 0; i < 4; i++) {
    int row = (tid >> 5) + i * 8;
    if (c0 + row < Cc && r0 + col < R) d[(size_t)(c0 + row) * R + r0 + col] = t[col][row];
  }
}

// ---- depthwise 3x3 stride-2 conv, dual-dtype x, arena weights, bf16 out ----
__global__ __launch_bounds__(256) void dwconv_k(const void* __restrict__ x,
                                                const u16* __restrict__ arena,
                                                u16* __restrict__ ki, u16* __restrict__ vi,
                                                const int* __restrict__ cnt) {
  int f32m = (*cnt >= 64);
  int b = blockIdx.x >> 8;
  int c = blockIdx.x & 255;
  float wkf[9], wvf[9];
#pragma unroll
  for (int t = 0; t < 9; t++) {
    wkf[t] = bf2f(arena[AOFF_WKDW + c * 9 + t]);
    wvf[t] = bf2f(arena[AOFF_WVDW + c * 9 + t]);
  }
  float kb = bf2f(arena[AOFF_BKDW + c]), vb = bf2f(arena[AOFF_BVDW + c]);
  size_t xbase = (size_t)(b * 256 + c) * HW;
  auto body = [&](auto LDX) {
    for (int j = threadIdx.x; j < KW; j += 256) {
      int oi = j / 28, oj = j % 28;
      float ka = kb, va = vb;
#pragma unroll
      for (int di = 0; di < 3; di++) {
        int ii = 2 * oi - 1 + di;
        if ((unsigned)ii >= 56u) continue;
#pragma unroll
        for (int dj = 0; dj < 3; dj++) {
          int ij = 2 * oj - 1 + dj;
          if ((unsigned)ij >= 56u) continue;
          float xv = LDX(ii * 56 + ij);
          ka += xv * wkf[di * 3 + dj];
          va += xv * wvf[di * 3 + dj];
        }
      }
      ki[(size_t)(b * 256 + c) * KW + j] = f2bf(ka);
      vi[(size_t)(b * 256 + c) * KW + j] = f2bf(va);
    }
  };
  if (f32m) {
    const float* xp = (const float*)x + xbase;
    body([&](int i) { return xp[i]; });
  } else {
    const u16* xp = (const u16*)x + xbase;
    body([&](int i) { return bf2f(xp[i]); });
  }
}

// ---- Q projection: q[b][p][o] = alpha * sum_c xt[b][p][c]*Wq[o][c] + beta[o] ----
__global__ __launch_bounds__(256) void proj_q_k(const u16* __restrict__ xt, const u16* __restrict__ Wq,
                                                const float* __restrict__ wsf, u16* __restrict__ q) {
  int lane = threadIdx.x & 63, wave = threadIdx.x >> 6;
  int l15 = lane & 15, quad = lane >> 4;
  int b = blockIdx.x / 49, pb = blockIdx.x % 49;
  int p0 = pb * 64 + wave * 16;
  const u16* arow = xt + ((size_t)(b * HW) + p0 + l15) * 256 + quad * 8;
  short8 af[8];
#pragma unroll
  for (int ks = 0; ks < 8; ks++) af[ks] = *(const short8*)(arow + ks * 32);
  float alpha = wsf[6];
  const float* beta = wsf + 16;
  for (int ot = 0; ot < 16; ot++) {
    const u16* brow = Wq + (size_t)(ot * 16 + l15) * 256 + quad * 8;
    f32x4 acc = {0.f, 0.f, 0.f, 0.f};
#pragma unroll
    for (int ks = 0; ks < 8; ks++) acc = MFMA16(af[ks], *(const short8*)(brow + ks * 32), acc);
    int o = ot * 16 + l15;
    float bet = beta[o];
    size_t base = ((size_t)(b * HW) + p0 + quad * 4) * 256 + o;
#pragma unroll
    for (int r = 0; r < 4; r++) q[base + (size_t)r * 256] = f2bf(alpha * acc[r] + bet);
  }
}

// ---- K projection ----
__global__ __launch_bounds__(256) void proj_k_k(const u16* __restrict__ kit, const u16* __restrict__ Wk,
                                                const u16* __restrict__ bk, u16* __restrict__ kout) {
  int lane = threadIdx.x & 63, wave = threadIdx.x >> 6;
  int l15 = lane & 15, quad = lane >> 4;
  int b = blockIdx.x / 13, jb = blockIdx.x % 13;
  int p0 = jb * 64 + wave * 16;
  if (p0 >= KW) return;
  const u16* arow = kit + ((size_t)(b * KW) + p0 + l15) * 256 + quad * 8;
  short8 af[8];
#pragma unroll
  for (int ks = 0; ks < 8; ks++) af[ks] = *(const short8*)(arow + ks * 32);
  for (int ot = 0; ot < 16; ot++) {
    const u16* brow = Wk + (size_t)(ot * 16 + l15) * 256 + quad * 8;
    f32x4 acc = {0.f, 0.f, 0.f, 0.f};
#pragma unroll
    for (int ks = 0; ks < 8; ks++) acc = MFMA16(af[ks], *(const short8*)(brow + ks * 32), acc);
    int o = ot * 16 + l15;
    float bias = bf2f(bk[o]);
    size_t base = ((size_t)(b * KW) + p0 + quad * 4) * 256 + o;
#pragma unroll
    for (int r = 0; r < 4; r++) kout[base + (size_t)r * 256] = f2bf(acc[r] + bias);
  }
}

// ---- V projection, transposed output vT[b][o][j] ----
__global__ __launch_bounds__(256) void proj_v_k(const u16* __restrict__ Wv, const u16* __restrict__ vit,
                                                const u16* __restrict__ bv, u16* __restrict__ vT) {
  int lane = threadIdx.x & 63, wave = threadIdx.x >> 6;
  int l15 = lane & 15, quad = lane >> 4;
  int b = blockIdx.x >> 4;
  int ob = (blockIdx.x >> 2) & 3;
  int js = blockIdx.x & 3;
  int o0 = ob * 64 + wave * 16;
  const u16* arow = Wv + (size_t)(o0 + l15) * 256 + quad * 8;
  short8 af[8];
#pragma unroll
  for (int ks = 0; ks < 8; ks++) af[ks] = *(const short8*)(arow + ks * 32);
  int jt0 = js * 13;
  int jt1 = (jt0 + 13 < 49) ? jt0 + 13 : 49;
  for (int jt = jt0; jt < jt1; jt++) {
    const u16* brow = vit + ((size_t)(b * KW) + jt * 16 + l15) * 256 + quad * 8;
    f32x4 acc = {0.f, 0.f, 0.f, 0.f};
#pragma unroll
    for (int ks = 0; ks < 8; ks++) acc = MFMA16(af[ks], *(const short8*)(brow + ks * 32), acc);
#pragma unroll
    for (int r = 0; r < 4; r++) {
      int o = o0 + quad * 4 + r;
      vT[((size_t)(b * 256) + o) * KW + jt * 16 + l15] = f2bf(acc[r] + bf2f(bv[o]));
    }
  }
}

// ---- fused attention v2: swapped-operand QK^T, single-pass no-max softmax, no LDS ----
// One wave handles (b, h, 32 q-rows). Scores: mfma(K,Q) -> lane (l15,quad) holds
// P[qrow=l15][key=jt*16+quad*4+r]. exp applied directly (|s| bounded; clamp 30 for safety).
// P redistributed to MFMA A-fragment layout with 16 shfls per 32-key chunk.
template <typename LD>
__device__ __forceinline__ void attn_body(const u16* __restrict__ qptr, const u16* __restrict__ kptr,
                                          const u16* __restrict__ vptr, u16* __restrict__ Ob,
                                          int b, int h, int p0, LD ldb) {
  int lane = threadIdx.x & 63;
  int l15 = lane & 15, quad = lane >> 4;
  const u16* qp = qptr + ((size_t)(b * HW) + p0 + l15) * 256 + h * 32 + quad * 8;
  short8 qf0 = *(const short8*)qp;             // q-rows p0..p0+15 (subtile 0)
  short8 qf1 = *(const short8*)(qp + 16 * 256);  // q-rows p0+16..p0+31 (subtile 1)
  const u16* kb = kptr + (size_t)b * KW * 256 + h * 32 + quad * 8;
  const u16* vb = vptr + ((size_t)(b * 256) + h * 32) * KW;
  const f32x4 zz = {0.f, 0.f, 0.f, 0.f};
  f32x4 o00 = zz, o01 = zz, o10 = zz, o11 = zz;
  float ls0 = 0.f, ls1 = 0.f;
  int sl0 = l15 + ((quad & 1) << 5);  // src lane for low half of pf
  bool hiq = (quad >= 2);             // this quad consumes tile B of the chunk

  auto tile = [&](int jt, u32& q00, u32& q01, u32& q10, u32& q11) {
    short8 kf = *(const short8*)(kb + (size_t)(jt * 16 + l15) * 256);
    f32x4 s0 = MFMA16(kf, qf0, zz);   // D[key local][qrow]: row=quad*4+r key, col=l15 qrow
    f32x4 s1 = MFMA16(kf, qf1, zz);
    f32x4 b0 = ldb(0, jt), b1 = ldb(1, jt);
    float e00 = __expf(fminf(s0[0] + b0[0], 30.f));
    float e01 = __expf(fminf(s0[1] + b0[1], 30.f));
    float e02 = __expf(fminf(s0[2] + b0[2], 30.f));
    float e03 = __expf(fminf(s0[3] + b0[3], 30.f));
    float e10 = __expf(fminf(s1[0] + b1[0], 30.f));
    float e11 = __expf(fminf(s1[1] + b1[1], 30.f));
    float e12 = __expf(fminf(s1[2] + b1[2], 30.f));
    float e13 = __expf(fminf(s1[3] + b1[3], 30.f));
    ls0 += (e00 + e01) + (e02 + e03);
    ls1 += (e10 + e11) + (e12 + e13);
    q00 = cvtpk(e00, e01); q01 = cvtpk(e02, e03);
    q10 = cvtpk(e10, e11); q11 = cvtpk(e12, e13);
  };
  // build A-frag short8 for 32-key chunk: lane (l15,quad) needs keys quad*8..quad*8+7
  auto gather = [&](u32 pa0, u32 pa1, u32 pb0, u32 pb1) -> short8 {
    u32 a0 = (u32)__shfl((int)pa0, sl0);
    u32 a1 = (u32)__shfl((int)pa1, sl0);
    u32 a2 = (u32)__shfl((int)pa0, sl0 + 16);
    u32 a3 = (u32)__shfl((int)pa1, sl0 + 16);
    u32 c0 = (u32)__shfl((int)pb0, sl0);
    u32 c1 = (u32)__shfl((int)pb1, sl0);
    u32 c2 = (u32)__shfl((int)pb0, sl0 + 16);
    u32 c3 = (u32)__shfl((int)pb1, sl0 + 16);
    union { u32 u[4]; short8 s; } w;
    w.u[0] = hiq ? c0 : a0; w.u[1] = hiq ? c1 : a1;
    w.u[2] = hiq ? c2 : a2; w.u[3] = hiq ? c3 : a3;
    return w.s;
  };
  auto pv = [&](int ch, short8 pf0, short8 pf1) {
    int jo = ch * 32 + quad * 8;
    if (jo > 776) jo = 776;  // clamp; those keys only meet P==0 (j>=784 pad)
    short8 v0 = *(const short8*)(vb + (size_t)l15 * KW + jo);
    short8 v1 = *(const short8*)(vb + (size_t)(16 + l15) * KW + jo);
    o00 = MFMA16(pf0, v0, o00); o01 = MFMA16(pf0, v1, o01);
    o10 = MFMA16(pf1, v0, o10); o11 = MFMA16(pf1, v1, o11);
  };

#pragma unroll 2
  for (int ch = 0; ch < 24; ch++) {
    u32 a00, a01, a10, a11, b00, b01, b10, b11;
    tile(ch * 2, a00, a01, a10, a11);
    tile(ch * 2 + 1, b00, b01, b10, b11);
    pv(ch, gather(a00, a01, b00, b01), gather(a10, a11, b10, b11));
  }
  {  // epilogue: keys 768..783 (jt=48); tile B of this chunk is all-pad -> P=0
    u32 a00, a01, a10, a11;
    tile(48, a00, a01, a10, a11);
    pv(24, gather(a00, a01, 0u, 0u), gather(a10, a11, 0u, 0u));
  }
  ls0 += __shfl_xor(ls0, 16); ls0 += __shfl_xor(ls0, 32);
  ls1 += __shfl_xor(ls1, 16); ls1 += __shfl_xor(ls1, 32);
  float inv0 = 1.f / ls0, inv1 = 1.f / ls1;  // lane holds inv for q-row l15 (per subtile)
  size_t ob0 = ((size_t)(b * HW) + p0 + quad * 4) * 256 + h * 32 + l15;
#pragma unroll
  for (int r = 0; r < 4; r++) {
    float ia = __shfl(inv0, quad * 4 + r);  // inv for q-row quad*4+r
    float ib = __shfl(inv1, quad * 4 + r);
    Ob[ob0 + (size_t)(r * 256)] = f2bf(o00[r] * ia);
    Ob[ob0 + (size_t)(r * 256) + 16] = f2bf(o01[r] * ia);
    Ob[ob0 + (size_t)(16 * 256 + r * 256)] = f2bf(o10[r] * ib);
    Ob[ob0 + (size_t)(16 * 256 + r * 256) + 16] = f2bf(o11[r] * ib);
  }
}

// BMODE 0: bias from bf16 arena. BMODE 1: bias direct from input (dual dtype via cnt).
template <int BMODE>
__global__ __launch_bounds__(64) void attn_k(const u16* __restrict__ q, const u16* __restrict__ k,
                                             const u16* __restrict__ vT, const void* __restrict__ Bb,
                                             u16* __restrict__ Ob, const int* __restrict__ cnt) {
  int lane = threadIdx.x & 63;
  int l15 = lane & 15, quad = lane >> 4;
  int pt = blockIdx.x % 98;
  int t = blockIdx.x / 98;
  int h = t & 7, b = t >> 3;
  int p0 = pt * 32;
  size_t bbase = ((size_t)(h * HW) + p0 + l15) * KW + quad * 4;
  if constexpr (BMODE == 0) {
    const u16* bb = (const u16*)Bb;
    attn_body(q, k, vT, Ob, b, h, p0, [&](int sub, int jt) -> f32x4 {
      us4 v = *(const us4*)(bb + bbase + (size_t)(sub * 16) * KW + jt * 16);
      f32x4 r = {bf2f(v[0]), bf2f(v[1]), bf2f(v[2]), bf2f(v[3])};
      return r;
    });
  } else {
    if (*cnt >= 64) {
      const float* bf = (const float*)Bb;
      attn_body(q, k, vT, Ob, b, h, p0, [&](int sub, int jt) -> f32x4 {
        float4 v = *(const float4*)(bf + bbase + (size_t)(sub * 16) * KW + jt * 16);
        f32x4 r = {v.x, v.y, v.z, v.w};
        return r;
      });
    } else {
      const u16* bb = (const u16*)Bb;
      attn_body(q, k, vT, Ob, b, h, p0, [&](int sub, int jt) -> f32x4 {
        us4 v = *(const us4*)(bb + bbase + (size_t)(sub * 16) * KW + jt * 16);
        f32x4 r = {bf2f(v[0]), bf2f(v[1]), bf2f(v[2]), bf2f(v[3])};
        return r;
      });
    }
  }
}

// ---- O projection + .view-quirk residual; dual-dtype x read and out write ----
__global__ __launch_bounds__(256) void proj_o_k(const u16* __restrict__ Ob, const u16* __restrict__ Wo,
                                                const u16* __restrict__ bo, const void* __restrict__ x,
                                                void* __restrict__ out, const int* __restrict__ cnt) {
  int f32m = (*cnt >= 64);
  int lane = threadIdx.x & 63, wave = threadIdx.x >> 6;
  int l15 = lane & 15, quad = lane >> 4;
  int b = blockIdx.x / 49, pb = blockIdx.x % 49;
  int p0 = pb * 64 + wave * 16;
  const u16* arow = Ob + ((size_t)(b * HW) + p0 + l15) * 256 + quad * 8;
  short8 af[8];
#pragma unroll
  for (int ks = 0; ks < 8; ks++) af[ks] = *(const short8*)(arow + ks * 32);
  for (int ot = 0; ot < 16; ot++) {
    const u16* brow = Wo + (size_t)(ot * 16 + l15) * 256 + quad * 8;
    f32x4 acc = {0.f, 0.f, 0.f, 0.f};
#pragma unroll
    for (int ks = 0; ks < 8; ks++) acc = MFMA16(af[ks], *(const short8*)(brow + ks * 32), acc);
    int o = ot * 16 + l15;
    float bias = bf2f(bo[o]);
    if (f32m) {
      const float* xf = (const float*)x;
      float* of = (float*)out;
#pragma unroll
      for (int r = 0; r < 4; r++) {
        size_t idx = ((size_t)(b * HW) + p0 + quad * 4 + r) * 256 + o;
        of[idx] = acc[r] + bias + xf[idx];
      }
    } else {
      const u16* xb = (const u16*)x;
      u16* ob_ = (u16*)out;
#pragma unroll
      for (int r = 0; r < 4; r++) {
        size_t idx = ((size_t)(b * HW) + p0 + quad * 4 + r) * 256 + o;
        ob_[idx] = f2bf(acc[r] + bias + bf2f(xb[idx]));
      }
    }
  }
}

extern "C" void kernel_launch(void* const* d_in, const int* in_sizes, int n_in,
                              void* d_out, int out_size, void* d_ws, size_t ws_size,
                              hipStream_t stream) {
  (void)in_sizes; (void)n_in; (void)out_size;
  const void* x = d_in[0];
  char* ws = (char*)d_ws;
  int* cnt = (int*)(ws + OFF_CNT);
  u16* arena = (u16*)(ws + OFF_W);
  u16* xt  = (u16*)(ws + OFF_XT);
  u16* kit = (u16*)(ws + OFF_KIT);
  u16* vit = (u16*)(ws + OFF_VIT);
  u16* ki  = (u16*)(ws + OFF_KI);   // then k-proj output
  u16* vi  = (u16*)(ws + OFF_VI);   // then vT
  u16* qb  = (u16*)(ws + OFF_Q);
  u16* Obuf = (u16*)(ws + OFF_O);   // overlays xt
  u16* bbA = (u16*)(ws + OFF_BB);
  bool big_ws = ws_size >= (OFF_BB + SZ_BB);

  CvtArgs a;
  const int srcidx[12] = {5, 7, 9, 11, 1, 3, 2, 4, 6, 8, 10, 12};
  const int dofs[12] = {AOFF_WQ, AOFF_WK, AOFF_WV, AOFF_WO, AOFF_WKDW, AOFF_WVDW,
                        AOFF_BKDW, AOFF_BVDW, AOFF_BQ, AOFF_BK, AOFF_BV, AOFF_BO};
  const int ns[12] = {65536, 65536, 65536, 65536, 2304, 2304, 256, 256, 256, 256, 256, 256};
  for (int i = 0; i < 12; i++) { a.src[i] = d_in[srcidx[i]]; a.dstoff[i] = dofs[i]; a.n[i] = ns[i]; }

  hipMemsetAsync(d_ws, 0, 8192, stream);  // zero acc + detect counter
  detect_k<<<1, 256, 0, stream>>>((const u32*)x, cnt);
  cvtw_k<<<dim3(32, 12), 256, 0, stream>>>(a, arena, cnt);
  if (big_ws) cvtb_k<<<2048, 256, 0, stream>>>(d_in[13], bbA, cnt);
  reduce_k<<<1024, 256, 0, stream>>>(x, (double*)d_ws, cnt);
  prep_k<<<1, 256, 0, stream>>>(arena + AOFF_WQ, arena + AOFF_BQ, (float*)d_ws);
  transpose_x_k<<<dim3(98, 8, 8), 256, 0, stream>>>(x, xt, cnt);
  dwconv_k<<<2048, 256, 0, stream>>>(x, arena, ki, vi, cnt);
  transpose_k<<<dim3(25, 8, 8), 256, 0, stream>>>(ki, kit, 256, KW);
  transpose_k<<<dim3(25, 8, 8), 256, 0, stream>>>(vi, vit, 256, KW);
  proj_k_k<<<104, 256, 0, stream>>>(kit, arena + AOFF_WK, arena + AOFF_BK, ki);
  proj_v_k<<<128, 256, 0, stream>>>(arena + AOFF_WV, vit, arena + AOFF_BV, vi);
  proj_q_k<<<392, 256, 0, stream>>>(xt, arena + AOFF_WQ, (const float*)d_ws, qb);
  if (big_ws) attn_k<0><<<6272, 64, 0, stream>>>(qb, ki, vi, bbA, Obuf, cnt);
  else        attn_k<1><<<6272, 64, 0, stream>>>(qb, ki, vi, d_in[13], Obuf, cnt);
  proj_o_k<<<392, 256, 0, stream>>>(Obuf, arena + AOFF_WO, arena + AOFF_BO, x, d_out, cnt);
}

// Round 4
// 451.321 us; speedup vs baseline: 1.1451x; 1.0580x over previous
//
#include <hip/hip_runtime.h>

typedef unsigned short u16;
typedef unsigned int   u32;
typedef __attribute__((ext_vector_type(8))) short short8;  // 8 bf16 (4 VGPRs)
typedef __attribute__((ext_vector_type(4))) float f32x4;
typedef __attribute__((ext_vector_type(4))) unsigned short us4;

#define MFMA16(a, b, c) __builtin_amdgcn_mfma_f32_16x16x32_bf16((a), (b), (c), 0, 0, 0)

static constexpr int B_ = 8;
static constexpr int HW = 3136;   // 56*56
static constexpr int KW = 784;    // 28*28
static constexpr int NELEM = B_ * 256 * HW;  // 6422528

// ---- workspace layout (bytes). Needs ~39.1 MB of d_ws. ----
static constexpr size_t OFF_CNT = 4096;   // int: dtype-detect counter (>=64 -> f32 inputs)
static constexpr size_t OFF_W   = 8192;   // bf16 weight arena
// arena offsets in u16 units
static constexpr int AOFF_WQ = 0, AOFF_WK = 65536, AOFF_WV = 131072, AOFF_WO = 196608;
static constexpr int AOFF_WKDW = 262144, AOFF_WVDW = 264448;
static constexpr int AOFF_BKDW = 266752, AOFF_BVDW = 267008, AOFF_BQ = 267264;
static constexpr int AOFF_BK = 267520, AOFF_BV = 267776, AOFF_BO = 268032;
static constexpr size_t OFF_XT  = 557056;
static constexpr size_t SZ_XT   = (size_t)B_ * HW * 256 * 2;  // 12845056
static constexpr size_t SZ_KJ   = (size_t)B_ * KW * 256 * 2;  // 3211264
static constexpr size_t OFF_KIT = OFF_XT + SZ_XT;
static constexpr size_t OFF_VIT = OFF_KIT + SZ_KJ;
static constexpr size_t OFF_KI  = OFF_VIT + SZ_KJ;  // conv-k out, later reused for k-proj out
static constexpr size_t OFF_VI  = OFF_KI + SZ_KJ;   // conv-v out, later reused for vT
static constexpr size_t OFF_Q   = OFF_VI + SZ_KJ;
static constexpr size_t OFF_O   = OFF_XT;           // overlays xt (dead after proj_q)

__device__ __forceinline__ float bf2f(u16 u) { return __uint_as_float(((u32)u) << 16); }
__device__ __forceinline__ u16 f2bf(float f) {
  u32 u = __float_as_uint(f);
  u32 r = u + 0x7FFFu + ((u >> 16) & 1u);
  return (u16)(r >> 16);
}
// HW packed f32->bf16 RNE (1 instr for 2 values); no builtin on gfx950, use asm.
__device__ __forceinline__ u32 cvtpk(float lo, float hi) {
  u32 r;
  asm("v_cvt_pk_bf16_f32 %0, %1, %2" : "=v"(r) : "v"(lo), "v"(hi));
  return r;
}

// ---- dtype detect: low 16 bits of first 4096 words of x, decoded as bf16.
__global__ __launch_bounds__(256) void detect_k(const u32* __restrict__ x, int* __restrict__ cnt) {
  int c = 0;
  for (int i = threadIdx.x; i < 4096; i += 256) {
    float v = __uint_as_float(x[i] << 16);
    if (fabsf(v) > 1e4f) c++;
  }
#pragma unroll
  for (int off = 32; off > 0; off >>= 1) c += __shfl_down(c, off);
  if ((threadIdx.x & 63) == 0) atomicAdd(cnt, c);
}

// ---- canonicalize 12 weight/bias tensors into bf16 arena ----
struct CvtArgs { const void* src[12]; int dstoff[12]; int n[12]; };
__global__ __launch_bounds__(256) void cvtw_k(CvtArgs a, u16* __restrict__ arena,
                                              const int* __restrict__ cnt) {
  int t = blockIdx.y;
  int n = a.n[t];
  u16* d = arena + a.dstoff[t];
  int f32m = (*cnt >= 64);
  if (f32m) {
    const float* s = (const float*)a.src[t];
    for (int i = blockIdx.x * 256 + threadIdx.x; i < n; i += gridDim.x * 256) d[i] = f2bf(s[i]);
  } else {
    const u16* s = (const u16*)a.src[t];
    for (int i = blockIdx.x * 256 + threadIdx.x; i < n; i += gridDim.x * 256) d[i] = s[i];
  }
}

// ---- global sum / sumsq of x (single-scalar LayerNorm), dual dtype ----
__global__ __launch_bounds__(256) void reduce_k(const void* __restrict__ x, double* __restrict__ acc,
                                                const int* __restrict__ cnt) {
  int f32m = (*cnt >= 64);
  float s = 0.f, ss = 0.f;
  if (f32m) {
    const float4* xv = (const float4*)x;
    const int n4 = NELEM / 4;
    for (int i = blockIdx.x * 256 + threadIdx.x; i < n4; i += gridDim.x * 256) {
      float4 u = xv[i];
      s += u.x + u.y + u.z + u.w;
      ss += u.x * u.x + u.y * u.y + u.z * u.z + u.w * u.w;
    }
  } else {
    const uint4* xv = (const uint4*)x;
    const int n8 = NELEM / 8;
    for (int i = blockIdx.x * 256 + threadIdx.x; i < n8; i += gridDim.x * 256) {
      uint4 u = xv[i];
      u32 w[4] = {u.x, u.y, u.z, u.w};
#pragma unroll
      for (int q = 0; q < 4; q++) {
        float f0 = __uint_as_float(w[q] << 16);
        float f1 = __uint_as_float(w[q] & 0xFFFF0000u);
        s += f0 + f1;
        ss += f0 * f0 + f1 * f1;
      }
    }
  }
#pragma unroll
  for (int off = 32; off > 0; off >>= 1) {
    s += __shfl_down(s, off);
    ss += __shfl_down(ss, off);
  }
  __shared__ float as_[4], ass_[4];
  int wv = threadIdx.x >> 6;
  if ((threadIdx.x & 63) == 0) { as_[wv] = s; ass_[wv] = ss; }
  __syncthreads();
  if (threadIdx.x == 0) {
    atomicAdd(acc + 0, (double)(as_[0] + as_[1] + as_[2] + as_[3]));
    atomicAdd(acc + 1, (double)(ass_[0] + ass_[1] + ass_[2] + ass_[3]));
  }
}

// ---- mu/rstd + folded Q-projection constants (weights already bf16 in arena) ----
__global__ __launch_bounds__(256) void prep_k(const u16* __restrict__ wq, const u16* __restrict__ bq,
                                              float* __restrict__ wsf) {
  const double* acc = (const double*)wsf;
  __shared__ float sh[2];
  if (threadIdx.x == 0) {
    double N = (double)NELEM;
    double mu = acc[0] / N;
    double var = acc[1] / N - mu * mu;
    float rstd = (float)(1.0 / sqrt(var + 1e-5));
    sh[0] = (float)mu; sh[1] = rstd;
    wsf[4] = (float)mu; wsf[5] = rstd;
    wsf[6] = rstd * 0.17677669529663687f;  // rstd / sqrt(32)
  }
  __syncthreads();
  int o = threadIdx.x;
  float wsum = 0.f;
  for (int c = 0; c < 256; c++) wsum += bf2f(wq[o * 256 + c]);
  wsf[16 + o] = (bf2f(bq[o]) - sh[1] * sh[0] * wsum) * 0.17677669529663687f;
}

// ---- x [b][256][3136] -> xt [b][3136][256], dual dtype, bf16 out ----
__global__ __launch_bounds__(256) void transpose_x_k(const void* __restrict__ src, u16* __restrict__ dst,
                                                     const int* __restrict__ cnt) {
  int f32m = (*cnt >= 64);
  __shared__ u16 t[32][33];
  int b = blockIdx.z;
  int r0 = blockIdx.y * 32, c0 = blockIdx.x * 32;
  int tid = threadIdx.x, col = tid & 31;
  size_t base = (size_t)b * 256 * HW;
  if (f32m) {
    const float* s = (const float*)src + base;
#pragma unroll
    for (int i = 0; i < 4; i++) {
      int row = (tid >> 5) + i * 8;
      t[row][col] = f2bf(s[(size_t)(r0 + row) * HW + c0 + col]);
    }
  } else {
    const u16* s = (const u16*)src + base;
#pragma unroll
    for (int i = 0; i < 4; i++) {
      int row = (tid >> 5) + i * 8;
      t[row][col] = s[(size_t)(r0 + row) * HW + c0 + col];
    }
  }
  __syncthreads();
  u16* d = dst + base;
#pragma unroll
  for (int i = 0; i < 4; i++) {
    int row = (tid >> 5) + i * 8;  // indexes HW-dim in dst
    d[(size_t)(c0 + row) * 256 + r0 + col] = t[col][row];
  }
}

// ---- generic bf16 per-batch [R][Cc] -> [Cc][R] transpose (for conv outputs) ----
__global__ __launch_bounds__(256) void transpose_k(const u16* __restrict__ src, u16* __restrict__ dst,
                                                   int R, int Cc) {
  __shared__ u16 t[32][33];
  int b = blockIdx.z;
  int r0 = blockIdx.y * 32, c0 = blockIdx.x * 32;
  const u16* s = src + (size_t)b * R * Cc;
  u16* d = dst + (size_t)b * R * Cc;
  int tid = threadIdx.x, col = tid & 31;
#pragma unroll
  for (int i = 0; i < 4; i++) {
    int row = (tid >> 5) + i * 8;
    if (r0 + row < R && c0 + col < Cc) t[row][col] = s[(size_t)(r0 + row) * Cc + c0 + col];
  }
  __syncthreads();
#pragma unroll
  for (int i = 0; i < 4; i++) {
    int row = (tid >> 5) + i * 8;
    if (c0 + row < Cc && r0 + col < R) d[(size_t)(c0 + row) * R + r0 + col] = t[col][row];
  }
}

// ---- depthwise 3x3 stride-2 conv, dual-dtype x, arena weights, bf16 out ----
__global__ __launch_bounds__(256) void dwconv_k(const void* __restrict__ x,
                                                const u16* __restrict__ arena,
                                                u16* __restrict__ ki, u16* __restrict__ vi,
                                                const int* __restrict__ cnt) {
  int f32m = (*cnt >= 64);
  int b = blockIdx.x >> 8;
  int c = blockIdx.x & 255;
  float wkf[9], wvf[9];
#pragma unroll
  for (int t = 0; t < 9; t++) {
    wkf[t] = bf2f(arena[AOFF_WKDW + c * 9 + t]);
    wvf[t] = bf2f(arena[AOFF_WVDW + c * 9 + t]);
  }
  float kb = bf2f(arena[AOFF_BKDW + c]), vb = bf2f(arena[AOFF_BVDW + c]);
  size_t xbase = (size_t)(b * 256 + c) * HW;
  auto body = [&](auto LDX) {
    for (int j = threadIdx.x; j < KW; j += 256) {
      int oi = j / 28, oj = j % 28;
      float ka = kb, va = vb;
#pragma unroll
      for (int di = 0; di < 3; di++) {
        int ii = 2 * oi - 1 + di;
        if ((unsigned)ii >= 56u) continue;
#pragma unroll
        for (int dj = 0; dj < 3; dj++) {
          int ij = 2 * oj - 1 + dj;
          if ((unsigned)ij >= 56u) continue;
          float xv = LDX(ii * 56 + ij);
          ka += xv * wkf[di * 3 + dj];
          va += xv * wvf[di * 3 + dj];
        }
      }
      ki[(size_t)(b * 256 + c) * KW + j] = f2bf(ka);
      vi[(size_t)(b * 256 + c) * KW + j] = f2bf(va);
    }
  };
  if (f32m) {
    const float* xp = (const float*)x + xbase;
    body([&](int i) { return xp[i]; });
  } else {
    const u16* xp = (const u16*)x + xbase;
    body([&](int i) { return bf2f(xp[i]); });
  }
}

// ---- Q projection: q[b][p][o] = alpha * sum_c xt[b][p][c]*Wq[o][c] + beta[o] ----
__global__ __launch_bounds__(256) void proj_q_k(const u16* __restrict__ xt, const u16* __restrict__ Wq,
                                                const float* __restrict__ wsf, u16* __restrict__ q) {
  int lane = threadIdx.x & 63, wave = threadIdx.x >> 6;
  int l15 = lane & 15, quad = lane >> 4;
  int b = blockIdx.x / 49, pb = blockIdx.x % 49;
  int p0 = pb * 64 + wave * 16;
  const u16* arow = xt + ((size_t)(b * HW) + p0 + l15) * 256 + quad * 8;
  short8 af[8];
#pragma unroll
  for (int ks = 0; ks < 8; ks++) af[ks] = *(const short8*)(arow + ks * 32);
  float alpha = wsf[6];
  const float* beta = wsf + 16;
  for (int ot = 0; ot < 16; ot++) {
    const u16* brow = Wq + (size_t)(ot * 16 + l15) * 256 + quad * 8;
    f32x4 acc = {0.f, 0.f, 0.f, 0.f};
#pragma unroll
    for (int ks = 0; ks < 8; ks++) acc = MFMA16(af[ks], *(const short8*)(brow + ks * 32), acc);
    int o = ot * 16 + l15;
    float bet = beta[o];
    size_t base = ((size_t)(b * HW) + p0 + quad * 4) * 256 + o;
#pragma unroll
    for (int r = 0; r < 4; r++) q[base + (size_t)r * 256] = f2bf(alpha * acc[r] + bet);
  }
}

// ---- K projection ----
__global__ __launch_bounds__(256) void proj_k_k(const u16* __restrict__ kit, const u16* __restrict__ Wk,
                                                const u16* __restrict__ bk, u16* __restrict__ kout) {
  int lane = threadIdx.x & 63, wave = threadIdx.x >> 6;
  int l15 = lane & 15, quad = lane >> 4;
  int b = blockIdx.x / 13, jb = blockIdx.x % 13;
  int p0 = jb * 64 + wave * 16;
  if (p0 >= KW) return;
  const u16* arow = kit + ((size_t)(b * KW) + p0 + l15) * 256 + quad * 8;
  short8 af[8];
#pragma unroll
  for (int ks = 0; ks < 8; ks++) af[ks] = *(const short8*)(arow + ks * 32);
  for (int ot = 0; ot < 16; ot++) {
    const u16* brow = Wk + (size_t)(ot * 16 + l15) * 256 + quad * 8;
    f32x4 acc = {0.f, 0.f, 0.f, 0.f};
#pragma unroll
    for (int ks = 0; ks < 8; ks++) acc = MFMA16(af[ks], *(const short8*)(brow + ks * 32), acc);
    int o = ot * 16 + l15;
    float bias = bf2f(bk[o]);
    size_t base = ((size_t)(b * KW) + p0 + quad * 4) * 256 + o;
#pragma unroll
    for (int r = 0; r < 4; r++) kout[base + (size_t)r * 256] = f2bf(acc[r] + bias);
  }
}

// ---- V projection, transposed output vT[b][o][j] ----
__global__ __launch_bounds__(256) void proj_v_k(const u16* __restrict__ Wv, const u16* __restrict__ vit,
                                                const u16* __restrict__ bv, u16* __restrict__ vT) {
  int lane = threadIdx.x & 63, wave = threadIdx.x >> 6;
  int l15 = lane & 15, quad = lane >> 4;
  int b = blockIdx.x >> 4;
  int ob = (blockIdx.x >> 2) & 3;
  int js = blockIdx.x & 3;
  int o0 = ob * 64 + wave * 16;
  const u16* arow = Wv + (size_t)(o0 + l15) * 256 + quad * 8;
  short8 af[8];
#pragma unroll
  for (int ks = 0; ks < 8; ks++) af[ks] = *(const short8*)(arow + ks * 32);
  int jt0 = js * 13;
  int jt1 = (jt0 + 13 < 49) ? jt0 + 13 : 49;
  for (int jt = jt0; jt < jt1; jt++) {
    const u16* brow = vit + ((size_t)(b * KW) + jt * 16 + l15) * 256 + quad * 8;
    f32x4 acc = {0.f, 0.f, 0.f, 0.f};
#pragma unroll
    for (int ks = 0; ks < 8; ks++) acc = MFMA16(af[ks], *(const short8*)(brow + ks * 32), acc);
#pragma unroll
    for (int r = 0; r < 4; r++) {
      int o = o0 + quad * 4 + r;
      vT[((size_t)(b * 256) + o) * KW + jt * 16 + l15] = f2bf(acc[r] + bf2f(bv[o]));
    }
  }
}

// ---- fused attention (PROVEN v2 math, verbatim): swapped-operand QK^T,
// single-pass no-max softmax, shuffle gather to A-layout, no LDS.
// Lane (l15,quad) after mfma(K,Q): P[qrow=l15][key=jt*16+quad*4+r].
template <typename LD>
__device__ __forceinline__ void attn_body(const u16* __restrict__ qptr, const u16* __restrict__ kptr,
                                          const u16* __restrict__ vptr, u16* __restrict__ Ob,
                                          int b, int h, int p0, LD ldb) {
  int lane = threadIdx.x & 63;
  int l15 = lane & 15, quad = lane >> 4;
  const u16* qp = qptr + ((size_t)(b * HW) + p0 + l15) * 256 + h * 32 + quad * 8;
  short8 qf0 = *(const short8*)qp;               // q-rows p0..p0+15 (subtile 0)
  short8 qf1 = *(const short8*)(qp + 16 * 256);  // q-rows p0+16..p0+31 (subtile 1)
  const u16* kb = kptr + (size_t)b * KW * 256 + h * 32 + quad * 8;
  const u16* vb = vptr + ((size_t)(b * 256) + h * 32) * KW;
  const f32x4 zz = {0.f, 0.f, 0.f, 0.f};
  f32x4 o00 = zz, o01 = zz, o10 = zz, o11 = zz;
  float ls0 = 0.f, ls1 = 0.f;
  int sl0 = l15 + ((quad & 1) << 5);  // src lane for low half of pf
  bool hiq = (quad >= 2);             // this quad consumes tile B of the chunk

  auto tile = [&](int jt, u32& q00, u32& q01, u32& q10, u32& q11) {
    short8 kf = *(const short8*)(kb + (size_t)(jt * 16 + l15) * 256);
    f32x4 s0 = MFMA16(kf, qf0, zz);   // D[key local][qrow]: row=quad*4+r key, col=l15 qrow
    f32x4 s1 = MFMA16(kf, qf1, zz);
    f32x4 b0 = ldb(0, jt), b1 = ldb(1, jt);
    float e00 = __expf(fminf(s0[0] + b0[0], 30.f));
    float e01 = __expf(fminf(s0[1] + b0[1], 30.f));
    float e02 = __expf(fminf(s0[2] + b0[2], 30.f));
    float e03 = __expf(fminf(s0[3] + b0[3], 30.f));
    float e10 = __expf(fminf(s1[0] + b1[0], 30.f));
    float e11 = __expf(fminf(s1[1] + b1[1], 30.f));
    float e12 = __expf(fminf(s1[2] + b1[2], 30.f));
    float e13 = __expf(fminf(s1[3] + b1[3], 30.f));
    ls0 += (e00 + e01) + (e02 + e03);
    ls1 += (e10 + e11) + (e12 + e13);
    q00 = cvtpk(e00, e01); q01 = cvtpk(e02, e03);
    q10 = cvtpk(e10, e11); q11 = cvtpk(e12, e13);
  };
  // build A-frag short8 for 32-key chunk: lane (l15,quad) needs keys quad*8..quad*8+7
  auto gather = [&](u32 pa0, u32 pa1, u32 pb0, u32 pb1) -> short8 {
    u32 a0 = (u32)__shfl((int)pa0, sl0);
    u32 a1 = (u32)__shfl((int)pa1, sl0);
    u32 a2 = (u32)__shfl((int)pa0, sl0 + 16);
    u32 a3 = (u32)__shfl((int)pa1, sl0 + 16);
    u32 c0 = (u32)__shfl((int)pb0, sl0);
    u32 c1 = (u32)__shfl((int)pb1, sl0);
    u32 c2 = (u32)__shfl((int)pb0, sl0 + 16);
    u32 c3 = (u32)__shfl((int)pb1, sl0 + 16);
    union { u32 u[4]; short8 s; } w;
    w.u[0] = hiq ? c0 : a0; w.u[1] = hiq ? c1 : a1;
    w.u[2] = hiq ? c2 : a2; w.u[3] = hiq ? c3 : a3;
    return w.s;
  };
  auto pv = [&](int ch, short8 pf0, short8 pf1) {
    int jo = ch * 32 + quad * 8;
    if (jo > 776) jo = 776;  // clamp; those keys only meet P==0 (j>=784 pad)
    short8 v0 = *(const short8*)(vb + (size_t)l15 * KW + jo);
    short8 v1 = *(const short8*)(vb + (size_t)(16 + l15) * KW + jo);
    o00 = MFMA16(pf0, v0, o00); o01 = MFMA16(pf0, v1, o01);
    o10 = MFMA16(pf1, v0, o10); o11 = MFMA16(pf1, v1, o11);
  };

#pragma unroll 2
  for (int ch = 0; ch < 24; ch++) {
    u32 a00, a01, a10, a11, b00, b01, b10, b11;
    tile(ch * 2, a00, a01, a10, a11);
    tile(ch * 2 + 1, b00, b01, b10, b11);
    pv(ch, gather(a00, a01, b00, b01), gather(a10, a11, b10, b11));
  }
  {  // epilogue: keys 768..783 (jt=48); tile B of this chunk is all-pad -> P=0
    u32 a00, a01, a10, a11;
    tile(48, a00, a01, a10, a11);
    pv(24, gather(a00, a01, 0u, 0u), gather(a10, a11, 0u, 0u));
  }
  ls0 += __shfl_xor(ls0, 16); ls0 += __shfl_xor(ls0, 32);
  ls1 += __shfl_xor(ls1, 16); ls1 += __shfl_xor(ls1, 32);
  float inv0 = 1.f / ls0, inv1 = 1.f / ls1;  // lane holds inv for q-row l15 (per subtile)
  size_t ob0 = ((size_t)(b * HW) + p0 + quad * 4) * 256 + h * 32 + l15;
#pragma unroll
  for (int r = 0; r < 4; r++) {
    float ia = __shfl(inv0, quad * 4 + r);  // inv for q-row quad*4+r
    float ib = __shfl(inv1, quad * 4 + r);
    Ob[ob0 + (size_t)(r * 256)] = f2bf(o00[r] * ia);
    Ob[ob0 + (size_t)(r * 256) + 16] = f2bf(o01[r] * ia);
    Ob[ob0 + (size_t)(16 * 256 + r * 256)] = f2bf(o10[r] * ib);
    Ob[ob0 + (size_t)(16 * 256 + r * 256) + 16] = f2bf(o11[r] * ib);
  }
}

// 256-thread blocks = 4 independent waves (lifts the workgroup/CU occupancy cap).
// Bias read directly from input (dual dtype via cnt); math identical to passing v2.
__global__ __launch_bounds__(256) void attn_k(const u16* __restrict__ q, const u16* __restrict__ k,
                                              const u16* __restrict__ vT, const void* __restrict__ Bb,
                                              u16* __restrict__ Ob, const int* __restrict__ cnt) {
  int lane = threadIdx.x & 63;
  int l15 = lane & 15, quad = lane >> 4;
  int task = blockIdx.x * 4 + (threadIdx.x >> 6);
  int pt = task % 98;
  int t = task / 98;
  int h = t & 7, b = t >> 3;
  int p0 = pt * 32;
  size_t bbase = ((size_t)(h * HW) + p0 + l15) * KW + quad * 4;
  if (*cnt >= 64) {
    const float* bf = (const float*)Bb;
    attn_body(q, k, vT, Ob, b, h, p0, [&](int sub, int jt) -> f32x4 {
      float4 v = *(const float4*)(bf + bbase + (size_t)(sub * 16) * KW + jt * 16);
      f32x4 r = {v.x, v.y, v.z, v.w};
      return r;
    });
  } else {
    const u16* bb = (const u16*)Bb;
    attn_body(q, k, vT, Ob, b, h, p0, [&](int sub, int jt) -> f32x4 {
      us4 v = *(const us4*)(bb + bbase + (size_t)(sub * 16) * KW + jt * 16);
      f32x4 r = {bf2f(v[0]), bf2f(v[1]), bf2f(v[2]), bf2f(v[3])};
      return r;
    });
  }
}

// ---- O projection + .view-quirk residual; dual-dtype x read and out write ----
__global__ __launch_bounds__(256) void proj_o_k(const u16* __restrict__ Ob, const u16* __restrict__ Wo,
                                                const u16* __restrict__ bo, const void* __restrict__ x,
                                                void* __restrict__ out, const int* __restrict__ cnt) {
  int f32m = (*cnt >= 64);
  int lane = threadIdx.x & 63, wave = threadIdx.x >> 6;
  int l15 = lane & 15, quad = lane >> 4;
  int b = blockIdx.x / 49, pb = blockIdx.x % 49;
  int p0 = pb * 64 + wave * 16;
  const u16* arow = Ob + ((size_t)(b * HW) + p0 + l15) * 256 + quad * 8;
  short8 af[8];
#pragma unroll
  for (int ks = 0; ks < 8; ks++) af[ks] = *(const short8*)(arow + ks * 32);
  for (int ot = 0; ot < 16; ot++) {
    const u16* brow = Wo + (size_t)(ot * 16 + l15) * 256 + quad * 8;
    f32x4 acc = {0.f, 0.f, 0.f, 0.f};
#pragma unroll
    for (int ks = 0; ks < 8; ks++) acc = MFMA16(af[ks], *(const short8*)(brow + ks * 32), acc);
    int o = ot * 16 + l15;
    float bias = bf2f(bo[o]);
    if (f32m) {
      const float* xf = (const float*)x;
      float* of = (float*)out;
#pragma unroll
      for (int r = 0; r < 4; r++) {
        size_t idx = ((size_t)(b * HW) + p0 + quad * 4 + r) * 256 + o;
        of[idx] = acc[r] + bias + xf[idx];
      }
    } else {
      const u16* xb = (const u16*)x;
      u16* ob_ = (u16*)out;
#pragma unroll
      for (int r = 0; r < 4; r++) {
        size_t idx = ((size_t)(b * HW) + p0 + quad * 4 + r) * 256 + o;
        ob_[idx] = f2bf(acc[r] + bias + bf2f(xb[idx]));
      }
    }
  }
}

extern "C" void kernel_launch(void* const* d_in, const int* in_sizes, int n_in,
                              void* d_out, int out_size, void* d_ws, size_t ws_size,
                              hipStream_t stream) {
  (void)in_sizes; (void)n_in; (void)out_size; (void)ws_size;
  const void* x = d_in[0];
  char* ws = (char*)d_ws;
  int* cnt = (int*)(ws + OFF_CNT);
  u16* arena = (u16*)(ws + OFF_W);
  u16* xt  = (u16*)(ws + OFF_XT);
  u16* kit = (u16*)(ws + OFF_KIT);
  u16* vit = (u16*)(ws + OFF_VIT);
  u16* ki  = (u16*)(ws + OFF_KI);   // then k-proj output
  u16* vi  = (u16*)(ws + OFF_VI);   // then vT
  u16* qb  = (u16*)(ws + OFF_Q);
  u16* Obuf = (u16*)(ws + OFF_O);   // overlays xt

  CvtArgs a;
  const int srcidx[12] = {5, 7, 9, 11, 1, 3, 2, 4, 6, 8, 10, 12};
  const int dofs[12] = {AOFF_WQ, AOFF_WK, AOFF_WV, AOFF_WO, AOFF_WKDW, AOFF_WVDW,
                        AOFF_BKDW, AOFF_BVDW, AOFF_BQ, AOFF_BK, AOFF_BV, AOFF_BO};
  const int ns[12] = {65536, 65536, 65536, 65536, 2304, 2304, 256, 256, 256, 256, 256, 256};
  for (int i = 0; i < 12; i++) { a.src[i] = d_in[srcidx[i]]; a.dstoff[i] = dofs[i]; a.n[i] = ns[i]; }

  hipMemsetAsync(d_ws, 0, 8192, stream);  // zero acc + detect counter
  detect_k<<<1, 256, 0, stream>>>((const u32*)x, cnt);
  cvtw_k<<<dim3(32, 12), 256, 0, stream>>>(a, arena, cnt);
  reduce_k<<<1024, 256, 0, stream>>>(x, (double*)d_ws, cnt);
  prep_k<<<1, 256, 0, stream>>>(arena + AOFF_WQ, arena + AOFF_BQ, (float*)d_ws);
  transpose_x_k<<<dim3(98, 8, 8), 256, 0, stream>>>(x, xt, cnt);
  dwconv_k<<<2048, 256, 0, stream>>>(x, arena, ki, vi, cnt);
  transpose_k<<<dim3(25, 8, 8), 256, 0, stream>>>(ki, kit, 256, KW);
  transpose_k<<<dim3(25, 8, 8), 256, 0, stream>>>(vi, vit, 256, KW);
  proj_k_k<<<104, 256, 0, stream>>>(kit, arena + AOFF_WK, arena + AOFF_BK, ki);
  proj_v_k<<<128, 256, 0, stream>>>(arena + AOFF_WV, vit, arena + AOFF_BV, vi);
  proj_q_k<<<392, 256, 0, stream>>>(xt, arena + AOFF_WQ, (const float*)d_ws, qb);
  attn_k<<<1568, 256, 0, stream>>>(qb, ki, vi, d_in[13], Obuf, cnt);
  proj_o_k<<<392, 256, 0, stream>>>(Obuf, arena + AOFF_WO, arena + AOFF_BO, x, d_out, cnt);
}